// Round 11
// baseline (213.118 us; speedup 1.0000x reference)
//
#include <hip/hip_runtime.h>
#include <hip/hip_fp16.h>

// GCN encoder, 3 layers. g = (X W) * dinv[row] stored FP16.
// out[d] = dinv[d]*(sum_{s->d} g[s] + g[d]) + b, accumulate fp32.
// GEMMs via v_mfma_f32_16x16x16_f16; W pre-transposed fp16 image.
// Aggregate: reduction-free (lane owns a half2 feature slice) + FEATURE-SPLIT:
// for F=64 each block handles one 64B half-row; half = bid&1 correlates with
// XCD parity -> each XCD only fetches half the bytes (compulsory-miss cut).
// 8 rows in flight per lane group. CSR build: fixed-capacity buckets.

#define BSH 7                    // 128 nodes per bucket
#define BNODES (1 << BSH)
#define NBUCKET_MAX 1024
#define CAPSH 12                 // 4096 edge slots per bucket
#define BIN_T 1024
#define BIN_E 4                  // edges per thread in k_bin

typedef __attribute__((ext_vector_type(4))) _Float16 half4v;
typedef __attribute__((ext_vector_type(4))) float float4v;

__global__ void k_binit0(int* __restrict__ bcur, int nb) {
    int b = blockIdx.x * blockDim.x + threadIdx.x;
    if (b < nb) bcur[b] = b << CAPSH;
}

// bin edges into buckets of 128 dst nodes; packed word = (src<<7)|(dst&127).
__global__ __launch_bounds__(BIN_T) void k_bin(
    const int* __restrict__ src, const int* __restrict__ dst,
    int* __restrict__ bcur, unsigned* __restrict__ ebin, int e, int nb) {
    __shared__ int hist[NBUCKET_MAX];
    const int tid = threadIdx.x;
    for (int b = tid; b < nb; b += BIN_T) hist[b] = 0;
    __syncthreads();

    const int base = blockIdx.x * (BIN_T * BIN_E);
    int      bk[BIN_E];
    unsigned pk[BIN_E];
#pragma unroll
    for (int j = 0; j < BIN_E; ++j) {
        int idx = base + j * BIN_T + tid;
        bk[j] = -1;
        if (idx < e) {
            int d = dst[idx], s = src[idx];
            bk[j] = d >> BSH;
            pk[j] = ((unsigned)s << BSH) | (unsigned)(d & (BNODES - 1));
            atomicAdd(&hist[bk[j]], 1);
        }
    }
    __syncthreads();
    for (int b = tid; b < nb; b += BIN_T) {
        int c = hist[b];
        hist[b] = c ? atomicAdd(&bcur[b], c) : 0;   // hist now = running cursor
    }
    __syncthreads();
#pragma unroll
    for (int j = 0; j < BIN_E; ++j) {
        if (bk[j] >= 0) {
            int pos = atomicAdd(&hist[bk[j]], 1);
            ebin[pos] = pk[j];
        }
    }
}

// per bucket: LDS node-histogram + 128-scan -> per-node cnt/offs/dinv
// (bucket-strided offsets), then place srcs into per-node CSR slots.
__global__ __launch_bounds__(256) void k_place2(
    const unsigned* __restrict__ ebin, const int* __restrict__ bcur,
    int* __restrict__ esrc, int* __restrict__ cnt, int* __restrict__ offs,
    float* __restrict__ dinv, int n) {
    __shared__ int hist[BNODES];
    __shared__ int loff[BNODES];
    __shared__ int cur[BNODES];
    const int b = blockIdx.x, tid = threadIdx.x;
    const int node0 = b << BSH;
    const int start = b << CAPSH;
    const int end   = bcur[b];
    if (tid < BNODES) hist[tid] = 0;
    __syncthreads();
    for (int j = start + tid; j < end; j += 256)
        atomicAdd(&hist[ebin[j] & (BNODES - 1)], 1);
    __syncthreads();
    int v = (tid < BNODES) ? hist[tid] : 0;
    if (tid < BNODES) loff[tid] = v;
    __syncthreads();
    for (int off = 1; off < BNODES; off <<= 1) {
        int add = (tid < BNODES && tid >= off) ? loff[tid - off] : 0;
        __syncthreads();
        if (tid < BNODES) loff[tid] += add;
        __syncthreads();
    }
    if (tid < BNODES) {
        int o = start + loff[tid] - v;   // exclusive, bucket-strided
        cur[tid] = o;
        int node = node0 + tid;
        if (node < n) {
            cnt[node]  = v;
            offs[node] = o;
            dinv[node] = rsqrtf((float)(v + 1));  // +1 self-loop
        }
    }
    __syncthreads();
    for (int j = start + tid; j < end; j += 256) {
        unsigned p = ebin[j];
        int pos = atomicAdd(&cur[p & (BNODES - 1)], 1);
        esrc[pos] = (int)(p >> BSH);
    }
}

// prep: W[k][f] (fp32) -> wt_img[f][k] (fp16, row stride K+8, LDS-ready)
__global__ __launch_bounds__(256) void k_wprep(
    const float* __restrict__ W1, const float* __restrict__ W2,
    const float* __restrict__ W3, __half* __restrict__ wt1,
    __half* __restrict__ wt2, __half* __restrict__ wt3) {
    int gid = blockIdx.x * 256 + threadIdx.x;
    if (gid < 8192) {                       // W1: 128x64, KP=136
        int k = gid >> 6, f = gid & 63;
        wt1[f * 136 + k] = __float2half(W1[gid]);
    } else if (gid < 12288) {               // W2: 64x64, KP=72
        int i = gid - 8192;
        int k = i >> 6, f = i & 63;
        wt2[f * 72 + k] = __float2half(W2[i]);
    } else if (gid < 14336) {               // W3: 64x32, KP=72
        int i = gid - 12288;
        int k = i >> 5, f = i & 31;
        wt3[f * 72 + k] = __float2half(W3[i]);
    }
}

// MFMA GEMM: g[node][f] = fp16( dinv[node] * sum_k in[node][k] * W[k][f] )
// 64-node tile per block, 4 waves x 16 rows; v_mfma_f32_16x16x16_f16.
// W comes pre-transposed/padded (wt_img, stride KP) -> flat uint4 copy.
template <int K, int F, typename InT>
__global__ __launch_bounds__(256) void k_gemm_mfma(
    const InT* __restrict__ in, const __half* __restrict__ wt_img,
    const float* __restrict__ dinv, __half* __restrict__ g, int n) {
    constexpr int KP = K + 8;         // padded halves per row
    constexpr int FP = F + 8;
    constexpr int NT = 64;            // nodes per block
    constexpr int CT = F / 16;        // col tiles per wave
    __shared__ __align__(16) __half xs[NT][KP];
    __shared__ __align__(16) __half wt[F][KP];   // wt[f][k] = W[k][f]
    const int tid = threadIdx.x;
    const int node0 = blockIdx.x * NT;

    // stage x tile -> fp16
    if constexpr (sizeof(InT) == 4) {
        constexpr int KW = K / 4;     // float4 per row
        const float4* in4 = reinterpret_cast<const float4*>(in);
        for (int i = tid; i < NT * KW; i += 256) {
            int r = i / KW, c = (i % KW) * 4;
            if (node0 + r < n) {
                float4 v = in4[(size_t)(node0 + r) * KW + (i % KW)];
                union { __half2 h2[2]; uint2 u; } pk;
                pk.h2[0] = __floats2half2_rn(v.x, v.y);
                pk.h2[1] = __floats2half2_rn(v.z, v.w);
                *reinterpret_cast<uint2*>(&xs[r][c]) = pk.u;
            }
        }
    } else {
        constexpr int KW = K / 8;     // uint4 per row
        const uint4* in4 = reinterpret_cast<const uint4*>(in);
        for (int i = tid; i < NT * KW; i += 256) {
            int r = i / KW, c = (i % KW) * 8;
            if (node0 + r < n)
                *reinterpret_cast<uint4*>(&xs[r][c]) =
                    in4[(size_t)(node0 + r) * KW + (i % KW)];
        }
    }
    // stage W image (already transposed fp16, stride KP): flat copy
    {
        const uint4* wim = reinterpret_cast<const uint4*>(wt_img);
        uint4* wt4 = reinterpret_cast<uint4*>(&wt[0][0]);
        for (int i = tid; i < F * KP / 8; i += 256) wt4[i] = wim[i];
    }
    __syncthreads();

    const int wid = tid >> 6, lane = tid & 63;
    const int rl = lane & 15;         // row within row-tile / col within col-tile
    const int kb = (lane >> 4) * 4;   // k base for this lane
    const int arow = wid * 16 + rl;

    float4v acc[CT];
#pragma unroll
    for (int c = 0; c < CT; ++c) acc[c] = (float4v)(0.f);

#pragma unroll
    for (int kk = 0; kk < K / 16; ++kk) {
        union { uint2 u; half4v h; } a;
        a.u = *reinterpret_cast<const uint2*>(&xs[arow][kk * 16 + kb]);
#pragma unroll
        for (int c = 0; c < CT; ++c) {
            union { uint2 u; half4v h; } b;
            b.u = *reinterpret_cast<const uint2*>(&wt[c * 16 + rl][kk * 16 + kb]);
            acc[c] = __builtin_amdgcn_mfma_f32_16x16x16f16(a.h, b.h, acc[c], 0, 0, 0);
        }
    }
    __syncthreads();   // xs dead; reuse as hs

    __half (*hs)[FP] = reinterpret_cast<__half (*)[FP]>(&xs[0][0]);
    float dv[4];
#pragma unroll
    for (int i = 0; i < 4; ++i) {
        int r = wid * 16 + (lane >> 4) * 4 + i;
        dv[i] = (node0 + r < n) ? dinv[node0 + r] : 0.f;
    }
#pragma unroll
    for (int c = 0; c < CT; ++c)
#pragma unroll
        for (int i = 0; i < 4; ++i) {
            int r = wid * 16 + (lane >> 4) * 4 + i;
            hs[r][c * 16 + rl] = __float2half(acc[c][i] * dv[i]);
        }
    __syncthreads();
    // coalesced writeout: uint4 = 8 halves
    constexpr int FW = F / 8;
    for (int i = tid; i < NT * FW; i += 256) {
        int r = i / FW, c = (i % FW) * 8;
        if (node0 + r < n)
            *reinterpret_cast<uint4*>(&g[(size_t)(node0 + r) * F + c]) =
                *reinterpret_cast<const uint4*>(&hs[r][c]);
    }
}

// Aggregate + finalize, reduction-free + feature-split.
// CHUNK features (one 64B line for CHUNK=32) per block; NHALF = F/CHUNK blocks
// cover a node. half = bid % NHALF correlates with XCD parity under round-robin
// block->XCD mapping, so each XCD touches only its half of every g row.
// Lane owns features (2*fl, 2*fl+1); 8 rows in flight; pairwise fp16 presum.
template <int F, int CHUNK, bool RELU, bool HOUT>
__global__ __launch_bounds__(256, 8) void k_agg(
    const __half* __restrict__ gin, const int* __restrict__ offs,
    const int* __restrict__ cnt, const int* __restrict__ esrc,
    const float* __restrict__ dinv, const float* __restrict__ bias,
    __half* __restrict__ hout, float* __restrict__ fout, int n) {
    constexpr int NHALF = F / CHUNK;    // blocks per node (feature halves)
    constexpr int LPN = CHUNK / 2;      // lanes per node-half (half2 each)
    constexpr int NPW = 64 / LPN;       // node-halves per wave
    const int bid  = blockIdx.x;
    const int half = (NHALF > 1) ? (bid & (NHALF - 1)) : 0;
    const int nblk = (NHALF > 1) ? (bid / NHALF) : bid;
    const int wid  = threadIdx.x >> 6;
    const int lane = threadIdx.x & 63;
    const int sub  = lane / LPN;
    const int fl   = lane % LPN;
    const int node = nblk * (4 * NPW) + wid * NPW + sub;   // grid exact
    const int start = offs[node];
    const int m     = cnt[node];
    constexpr int RS = F / 2;           // row stride in half2
    const __half2* gp = reinterpret_cast<const __half2*>(gin)
                        + half * LPN + fl;

    float accx = 0.f, accy = 0.f;
    int j = 0;
    for (; j + 8 <= m; j += 8) {        // 8 idx + 8 row loads in flight
        int i0 = esrc[start + j],     i1 = esrc[start + j + 1];
        int i2 = esrc[start + j + 2], i3 = esrc[start + j + 3];
        int i4 = esrc[start + j + 4], i5 = esrc[start + j + 5];
        int i6 = esrc[start + j + 6], i7 = esrc[start + j + 7];
        __half2 v0 = gp[(size_t)i0 * RS], v1 = gp[(size_t)i1 * RS];
        __half2 v2 = gp[(size_t)i2 * RS], v3 = gp[(size_t)i3 * RS];
        __half2 v4 = gp[(size_t)i4 * RS], v5 = gp[(size_t)i5 * RS];
        __half2 v6 = gp[(size_t)i6 * RS], v7 = gp[(size_t)i7 * RS];
        __half2 s01 = __hadd2(v0, v1);  // one fp16 add per pair (R9-proven)
        __half2 s23 = __hadd2(v2, v3);
        __half2 s45 = __hadd2(v4, v5);
        __half2 s67 = __hadd2(v6, v7);
        float2 f01 = __half22float2(s01), f23 = __half22float2(s23);
        float2 f45 = __half22float2(s45), f67 = __half22float2(s67);
        accx += (f01.x + f23.x) + (f45.x + f67.x);
        accy += (f01.y + f23.y) + (f45.y + f67.y);
    }
    for (; j + 4 <= m; j += 4) {
        int i0 = esrc[start + j],     i1 = esrc[start + j + 1];
        int i2 = esrc[start + j + 2], i3 = esrc[start + j + 3];
        __half2 v0 = gp[(size_t)i0 * RS], v1 = gp[(size_t)i1 * RS];
        __half2 v2 = gp[(size_t)i2 * RS], v3 = gp[(size_t)i3 * RS];
        __half2 s01 = __hadd2(v0, v1);
        __half2 s23 = __hadd2(v2, v3);
        float2 f01 = __half22float2(s01), f23 = __half22float2(s23);
        accx += f01.x + f23.x;
        accy += f01.y + f23.y;
    }
    for (; j < m; ++j) {
        float2 f = __half22float2(gp[(size_t)esrc[start + j] * RS]);
        accx += f.x; accy += f.y;
    }

    float2 sf = __half22float2(gp[(size_t)node * RS]);   // self-loop
    const float dv = dinv[node];
    float2 bv = *reinterpret_cast<const float2*>(bias + half * CHUNK + fl * 2);
    float rx = dv * (accx + sf.x) + bv.x;
    float ry = dv * (accy + sf.y) + bv.y;
    if (RELU) { rx = fmaxf(rx, 0.f); ry = fmaxf(ry, 0.f); }
    if (HOUT) {
        reinterpret_cast<__half2*>(hout)[(size_t)node * RS + half * LPN + fl] =
            __floats2half2_rn(rx, ry);
    } else {
        reinterpret_cast<float2*>(fout)[(size_t)node * RS + half * LPN + fl] =
            make_float2(rx, ry);
    }
}

extern "C" void kernel_launch(void* const* d_in, const int* in_sizes, int n_in,
                              void* d_out, int out_size, void* d_ws, size_t ws_size,
                              hipStream_t stream) {
    const float* x  = (const float*)d_in[0];
    const int*   ei = (const int*)d_in[1];
    const float* W1 = (const float*)d_in[2];
    const float* b1 = (const float*)d_in[3];
    const float* W2 = (const float*)d_in[4];
    const float* b2 = (const float*)d_in[5];
    const float* W3 = (const float*)d_in[6];
    const float* b3 = (const float*)d_in[7];
    float* out = (float*)d_out;

    const int n = in_sizes[0] / 128;   // 100000
    const int e = in_sizes[1] / 2;     // 1600000
    const int* src = ei;
    const int* dst = ei + e;

    const int nb = (n + BNODES - 1) >> BSH;  // 782

    // workspace layout (4-byte units)
    float*    dinv = (float*)d_ws;                     // n
    __half*   g    = (__half*)(dinv + n);              // n*64 halves
    __half*   h16  = (__half*)((int*)d_ws + n + (size_t)n * 32);  // n*64 halves
    int*      cnt  = (int*)d_ws + n + (size_t)n * 64;  // n
    int*      offs = cnt + n;                          // n
    int*      bcur = offs + n;                         // NBUCKET_MAX
    __half*   wt1  = (__half*)(bcur + NBUCKET_MAX);    // 64*136 halves
    __half*   wt2  = wt1 + 64 * 136;                   // 64*72
    __half*   wt3  = wt2 + 64 * 72;                    // 32*72
    unsigned* ebin = (unsigned*)(wt3 + 32 * 72 + 32);  // nb<<CAPSH
    int*      esrc = (int*)(ebin + ((size_t)nb << CAPSH));  // nb<<CAPSH

    const int B = 256;
    const int binGrid = (e + BIN_T * BIN_E - 1) / (BIN_T * BIN_E);

    // ---- CSR build (fixed-capacity buckets; emits cnt/offs/dinv) + W prep ----
    k_binit0<<<(nb + B - 1) / B, B, 0, stream>>>(bcur, nb);
    k_wprep<<<56, B, 0, stream>>>(W1, W2, W3, wt1, wt2, wt3);
    k_bin<<<binGrid, BIN_T, 0, stream>>>(src, dst, bcur, ebin, e, nb);
    k_place2<<<nb, B, 0, stream>>>(ebin, bcur, esrc, cnt, offs, dinv, n);

    // ---- layer 1: x[n x 128] @ W1 -> g (fp16) ; agg -> h16 (fp16) ----
    k_gemm_mfma<128, 64, float><<<(n + 63) / 64, B, 0, stream>>>(x, wt1, dinv, g, n);
    k_agg<64, 32, true, true><<<n / 8, B, 0, stream>>>(
        g, offs, cnt, esrc, dinv, b1, h16, nullptr, n);

    // ---- layer 2: h16 @ W2 -> g ; agg -> h16 ----
    k_gemm_mfma<64, 64, __half><<<(n + 63) / 64, B, 0, stream>>>(h16, wt2, dinv, g, n);
    k_agg<64, 32, true, true><<<n / 8, B, 0, stream>>>(
        g, offs, cnt, esrc, dinv, b2, h16, nullptr, n);

    // ---- layer 3: h16 @ W3 -> g (F=32) ; agg -> out (fp32) ----
    k_gemm_mfma<64, 32, __half><<<(n + 63) / 64, B, 0, stream>>>(h16, wt3, dinv, g, n);
    k_agg<32, 32, false, false><<<n / 16, B, 0, stream>>>(
        g, offs, cnt, esrc, dinv, b3, nullptr, out, n);
}

// Round 12
// 181.174 us; speedup vs baseline: 1.1763x; 1.1763x over previous
//
#include <hip/hip_runtime.h>
#include <hip/hip_fp16.h>

// GCN encoder, 3 layers. g = (X W) * dinv[row] stored FP16.
// out[d] = dinv[d]*(sum_{s->d} g[s] + g[d]) + b, accumulate fp32.
// GEMMs via v_mfma_f32_16x16x16_f16; W pre-transposed fp16 image.
// Aggregate: reduction-free, FULL row per lane group (R11 feature-split
// regressed: 128B L2 granule doubled fetches). 8 rows in flight per lane +
// high occupancy to raise outstanding L2 misses (L3-resident gather).
// CSR build: fixed-capacity buckets (4096 slots vs Poisson mean 2046).

#define BSH 7                    // 128 nodes per bucket
#define BNODES (1 << BSH)
#define NBUCKET_MAX 1024
#define CAPSH 12                 // 4096 edge slots per bucket
#define BIN_T 1024
#define BIN_E 4                  // edges per thread in k_bin

typedef __attribute__((ext_vector_type(4))) _Float16 half4v;
typedef __attribute__((ext_vector_type(4))) float float4v;

__global__ void k_binit0(int* __restrict__ bcur, int nb) {
    int b = blockIdx.x * blockDim.x + threadIdx.x;
    if (b < nb) bcur[b] = b << CAPSH;
}

// bin edges into buckets of 128 dst nodes; packed word = (src<<7)|(dst&127).
__global__ __launch_bounds__(BIN_T) void k_bin(
    const int* __restrict__ src, const int* __restrict__ dst,
    int* __restrict__ bcur, unsigned* __restrict__ ebin, int e, int nb) {
    __shared__ int hist[NBUCKET_MAX];
    const int tid = threadIdx.x;
    for (int b = tid; b < nb; b += BIN_T) hist[b] = 0;
    __syncthreads();

    const int base = blockIdx.x * (BIN_T * BIN_E);
    int      bk[BIN_E];
    unsigned pk[BIN_E];
#pragma unroll
    for (int j = 0; j < BIN_E; ++j) {
        int idx = base + j * BIN_T + tid;
        bk[j] = -1;
        if (idx < e) {
            int d = dst[idx], s = src[idx];
            bk[j] = d >> BSH;
            pk[j] = ((unsigned)s << BSH) | (unsigned)(d & (BNODES - 1));
            atomicAdd(&hist[bk[j]], 1);
        }
    }
    __syncthreads();
    for (int b = tid; b < nb; b += BIN_T) {
        int c = hist[b];
        hist[b] = c ? atomicAdd(&bcur[b], c) : 0;   // hist now = running cursor
    }
    __syncthreads();
#pragma unroll
    for (int j = 0; j < BIN_E; ++j) {
        if (bk[j] >= 0) {
            int pos = atomicAdd(&hist[bk[j]], 1);
            ebin[pos] = pk[j];
        }
    }
}

// per bucket: LDS node-histogram + 128-scan -> per-node cnt/offs/dinv
// (bucket-strided offsets), then place srcs into per-node CSR slots.
__global__ __launch_bounds__(256) void k_place2(
    const unsigned* __restrict__ ebin, const int* __restrict__ bcur,
    int* __restrict__ esrc, int* __restrict__ cnt, int* __restrict__ offs,
    float* __restrict__ dinv, int n) {
    __shared__ int hist[BNODES];
    __shared__ int loff[BNODES];
    __shared__ int cur[BNODES];
    const int b = blockIdx.x, tid = threadIdx.x;
    const int node0 = b << BSH;
    const int start = b << CAPSH;
    const int end   = bcur[b];
    if (tid < BNODES) hist[tid] = 0;
    __syncthreads();
    for (int j = start + tid; j < end; j += 256)
        atomicAdd(&hist[ebin[j] & (BNODES - 1)], 1);
    __syncthreads();
    int v = (tid < BNODES) ? hist[tid] : 0;
    if (tid < BNODES) loff[tid] = v;
    __syncthreads();
    for (int off = 1; off < BNODES; off <<= 1) {
        int add = (tid < BNODES && tid >= off) ? loff[tid - off] : 0;
        __syncthreads();
        if (tid < BNODES) loff[tid] += add;
        __syncthreads();
    }
    if (tid < BNODES) {
        int o = start + loff[tid] - v;   // exclusive, bucket-strided
        cur[tid] = o;
        int node = node0 + tid;
        if (node < n) {
            cnt[node]  = v;
            offs[node] = o;
            dinv[node] = rsqrtf((float)(v + 1));  // +1 self-loop
        }
    }
    __syncthreads();
    for (int j = start + tid; j < end; j += 256) {
        unsigned p = ebin[j];
        int pos = atomicAdd(&cur[p & (BNODES - 1)], 1);
        esrc[pos] = (int)(p >> BSH);
    }
}

// prep: W[k][f] (fp32) -> wt_img[f][k] (fp16, row stride K+8, LDS-ready)
__global__ __launch_bounds__(256) void k_wprep(
    const float* __restrict__ W1, const float* __restrict__ W2,
    const float* __restrict__ W3, __half* __restrict__ wt1,
    __half* __restrict__ wt2, __half* __restrict__ wt3) {
    int gid = blockIdx.x * 256 + threadIdx.x;
    if (gid < 8192) {                       // W1: 128x64, KP=136
        int k = gid >> 6, f = gid & 63;
        wt1[f * 136 + k] = __float2half(W1[gid]);
    } else if (gid < 12288) {               // W2: 64x64, KP=72
        int i = gid - 8192;
        int k = i >> 6, f = i & 63;
        wt2[f * 72 + k] = __float2half(W2[i]);
    } else if (gid < 14336) {               // W3: 64x32, KP=72
        int i = gid - 12288;
        int k = i >> 5, f = i & 31;
        wt3[f * 72 + k] = __float2half(W3[i]);
    }
}

// MFMA GEMM: g[node][f] = fp16( dinv[node] * sum_k in[node][k] * W[k][f] )
// 64-node tile per block, 4 waves x 16 rows; v_mfma_f32_16x16x16_f16.
// W comes pre-transposed/padded (wt_img, stride KP) -> flat uint4 copy.
template <int K, int F, typename InT>
__global__ __launch_bounds__(256) void k_gemm_mfma(
    const InT* __restrict__ in, const __half* __restrict__ wt_img,
    const float* __restrict__ dinv, __half* __restrict__ g, int n) {
    constexpr int KP = K + 8;         // padded halves per row
    constexpr int FP = F + 8;
    constexpr int NT = 64;            // nodes per block
    constexpr int CT = F / 16;        // col tiles per wave
    __shared__ __align__(16) __half xs[NT][KP];
    __shared__ __align__(16) __half wt[F][KP];   // wt[f][k] = W[k][f]
    const int tid = threadIdx.x;
    const int node0 = blockIdx.x * NT;

    // stage x tile -> fp16
    if constexpr (sizeof(InT) == 4) {
        constexpr int KW = K / 4;     // float4 per row
        const float4* in4 = reinterpret_cast<const float4*>(in);
        for (int i = tid; i < NT * KW; i += 256) {
            int r = i / KW, c = (i % KW) * 4;
            if (node0 + r < n) {
                float4 v = in4[(size_t)(node0 + r) * KW + (i % KW)];
                union { __half2 h2[2]; uint2 u; } pk;
                pk.h2[0] = __floats2half2_rn(v.x, v.y);
                pk.h2[1] = __floats2half2_rn(v.z, v.w);
                *reinterpret_cast<uint2*>(&xs[r][c]) = pk.u;
            }
        }
    } else {
        constexpr int KW = K / 8;     // uint4 per row
        const uint4* in4 = reinterpret_cast<const uint4*>(in);
        for (int i = tid; i < NT * KW; i += 256) {
            int r = i / KW, c = (i % KW) * 8;
            if (node0 + r < n)
                *reinterpret_cast<uint4*>(&xs[r][c]) =
                    in4[(size_t)(node0 + r) * KW + (i % KW)];
        }
    }
    // stage W image (already transposed fp16, stride KP): flat copy
    {
        const uint4* wim = reinterpret_cast<const uint4*>(wt_img);
        uint4* wt4 = reinterpret_cast<uint4*>(&wt[0][0]);
        for (int i = tid; i < F * KP / 8; i += 256) wt4[i] = wim[i];
    }
    __syncthreads();

    const int wid = tid >> 6, lane = tid & 63;
    const int rl = lane & 15;         // row within row-tile / col within col-tile
    const int kb = (lane >> 4) * 4;   // k base for this lane
    const int arow = wid * 16 + rl;

    float4v acc[CT];
#pragma unroll
    for (int c = 0; c < CT; ++c) acc[c] = (float4v)(0.f);

#pragma unroll
    for (int kk = 0; kk < K / 16; ++kk) {
        union { uint2 u; half4v h; } a;
        a.u = *reinterpret_cast<const uint2*>(&xs[arow][kk * 16 + kb]);
#pragma unroll
        for (int c = 0; c < CT; ++c) {
            union { uint2 u; half4v h; } b;
            b.u = *reinterpret_cast<const uint2*>(&wt[c * 16 + rl][kk * 16 + kb]);
            acc[c] = __builtin_amdgcn_mfma_f32_16x16x16f16(a.h, b.h, acc[c], 0, 0, 0);
        }
    }
    __syncthreads();   // xs dead; reuse as hs

    __half (*hs)[FP] = reinterpret_cast<__half (*)[FP]>(&xs[0][0]);
    float dv[4];
#pragma unroll
    for (int i = 0; i < 4; ++i) {
        int r = wid * 16 + (lane >> 4) * 4 + i;
        dv[i] = (node0 + r < n) ? dinv[node0 + r] : 0.f;
    }
#pragma unroll
    for (int c = 0; c < CT; ++c)
#pragma unroll
        for (int i = 0; i < 4; ++i) {
            int r = wid * 16 + (lane >> 4) * 4 + i;
            hs[r][c * 16 + rl] = __float2half(acc[c][i] * dv[i]);
        }
    __syncthreads();
    // coalesced writeout: uint4 = 8 halves
    constexpr int FW = F / 8;
    for (int i = tid; i < NT * FW; i += 256) {
        int r = i / FW, c = (i % FW) * 8;
        if (node0 + r < n)
            *reinterpret_cast<uint4*>(&g[(size_t)(node0 + r) * F + c]) =
                *reinterpret_cast<const uint4*>(&hs[r][c]);
    }
}

// Aggregate + finalize, reduction-free. One node per (F/2)-lane group;
// lane owns features (2*fl, 2*fl+1) exclusively. Edge indices uniform within
// the group (broadcast); 8 row loads in flight; pairwise fp16 presum.
// HOUT: write fp16 h row (next layer input); else fp32 to fout.
template <int F, bool RELU, bool HOUT>
__global__ __launch_bounds__(256, 8) void k_agg(
    const __half* __restrict__ gin, const int* __restrict__ offs,
    const int* __restrict__ cnt, const int* __restrict__ esrc,
    const float* __restrict__ dinv, const float* __restrict__ bias,
    __half* __restrict__ hout, float* __restrict__ fout, int n) {
    constexpr int LPN = F / 2;          // lanes per node (one half2 each)
    constexpr int NPW = 64 / LPN;       // nodes per wave
    const int wid  = threadIdx.x >> 6;
    const int lane = threadIdx.x & 63;
    const int sub  = lane / LPN;
    const int fl   = lane % LPN;
    const int node = (blockIdx.x * 4 + wid) * NPW + sub;  // grid exact
    const int start = offs[node];
    const int m     = cnt[node];
    const __half2* gp = reinterpret_cast<const __half2*>(gin) + fl;

    float accx = 0.f, accy = 0.f;
    int j = 0;
    for (; j + 8 <= m; j += 8) {        // 8 idx + 8 row loads in flight
        int i0 = esrc[start + j],     i1 = esrc[start + j + 1];
        int i2 = esrc[start + j + 2], i3 = esrc[start + j + 3];
        int i4 = esrc[start + j + 4], i5 = esrc[start + j + 5];
        int i6 = esrc[start + j + 6], i7 = esrc[start + j + 7];
        __half2 v0 = gp[(size_t)i0 * LPN], v1 = gp[(size_t)i1 * LPN];
        __half2 v2 = gp[(size_t)i2 * LPN], v3 = gp[(size_t)i3 * LPN];
        __half2 v4 = gp[(size_t)i4 * LPN], v5 = gp[(size_t)i5 * LPN];
        __half2 v6 = gp[(size_t)i6 * LPN], v7 = gp[(size_t)i7 * LPN];
        __half2 s01 = __hadd2(v0, v1);  // pairwise fp16 presum (R9-proven)
        __half2 s23 = __hadd2(v2, v3);
        __half2 s45 = __hadd2(v4, v5);
        __half2 s67 = __hadd2(v6, v7);
        float2 f01 = __half22float2(s01), f23 = __half22float2(s23);
        float2 f45 = __half22float2(s45), f67 = __half22float2(s67);
        accx += (f01.x + f23.x) + (f45.x + f67.x);
        accy += (f01.y + f23.y) + (f45.y + f67.y);
    }
    for (; j + 4 <= m; j += 4) {
        int i0 = esrc[start + j],     i1 = esrc[start + j + 1];
        int i2 = esrc[start + j + 2], i3 = esrc[start + j + 3];
        __half2 v0 = gp[(size_t)i0 * LPN], v1 = gp[(size_t)i1 * LPN];
        __half2 v2 = gp[(size_t)i2 * LPN], v3 = gp[(size_t)i3 * LPN];
        __half2 s01 = __hadd2(v0, v1);
        __half2 s23 = __hadd2(v2, v3);
        float2 f01 = __half22float2(s01), f23 = __half22float2(s23);
        accx += f01.x + f23.x;
        accy += f01.y + f23.y;
    }
    for (; j < m; ++j) {
        float2 f = __half22float2(gp[(size_t)esrc[start + j] * LPN]);
        accx += f.x; accy += f.y;
    }

    float2 sf = __half22float2(gp[(size_t)node * LPN]);   // self-loop
    const float dv = dinv[node];
    float2 bv = *reinterpret_cast<const float2*>(bias + fl * 2);
    float rx = dv * (accx + sf.x) + bv.x;
    float ry = dv * (accy + sf.y) + bv.y;
    if (RELU) { rx = fmaxf(rx, 0.f); ry = fmaxf(ry, 0.f); }
    if (HOUT) {
        reinterpret_cast<__half2*>(hout)[(size_t)node * LPN + fl] =
            __floats2half2_rn(rx, ry);
    } else {
        reinterpret_cast<float2*>(fout)[(size_t)node * LPN + fl] =
            make_float2(rx, ry);
    }
}

extern "C" void kernel_launch(void* const* d_in, const int* in_sizes, int n_in,
                              void* d_out, int out_size, void* d_ws, size_t ws_size,
                              hipStream_t stream) {
    const float* x  = (const float*)d_in[0];
    const int*   ei = (const int*)d_in[1];
    const float* W1 = (const float*)d_in[2];
    const float* b1 = (const float*)d_in[3];
    const float* W2 = (const float*)d_in[4];
    const float* b2 = (const float*)d_in[5];
    const float* W3 = (const float*)d_in[6];
    const float* b3 = (const float*)d_in[7];
    float* out = (float*)d_out;

    const int n = in_sizes[0] / 128;   // 100000
    const int e = in_sizes[1] / 2;     // 1600000
    const int* src = ei;
    const int* dst = ei + e;

    const int nb = (n + BNODES - 1) >> BSH;  // 782

    // workspace layout (4-byte units)
    float*    dinv = (float*)d_ws;                     // n
    __half*   g    = (__half*)(dinv + n);              // n*64 halves
    __half*   h16  = (__half*)((int*)d_ws + n + (size_t)n * 32);  // n*64 halves
    int*      cnt  = (int*)d_ws + n + (size_t)n * 64;  // n
    int*      offs = cnt + n;                          // n
    int*      bcur = offs + n;                         // NBUCKET_MAX
    __half*   wt1  = (__half*)(bcur + NBUCKET_MAX);    // 64*136 halves
    __half*   wt2  = wt1 + 64 * 136;                   // 64*72
    __half*   wt3  = wt2 + 64 * 72;                    // 32*72
    unsigned* ebin = (unsigned*)(wt3 + 32 * 72 + 32);  // nb<<CAPSH
    int*      esrc = (int*)(ebin + ((size_t)nb << CAPSH));  // nb<<CAPSH

    const int B = 256;
    const int binGrid = (e + BIN_T * BIN_E - 1) / (BIN_T * BIN_E);

    // ---- CSR build (fixed-capacity buckets; emits cnt/offs/dinv) + W prep ----
    k_binit0<<<(nb + B - 1) / B, B, 0, stream>>>(bcur, nb);
    k_wprep<<<56, B, 0, stream>>>(W1, W2, W3, wt1, wt2, wt3);
    k_bin<<<binGrid, BIN_T, 0, stream>>>(src, dst, bcur, ebin, e, nb);
    k_place2<<<nb, B, 0, stream>>>(ebin, bcur, esrc, cnt, offs, dinv, n);

    // ---- layer 1: x[n x 128] @ W1 -> g (fp16) ; agg -> h16 (fp16) ----
    k_gemm_mfma<128, 64, float><<<(n + 63) / 64, B, 0, stream>>>(x, wt1, dinv, g, n);
    k_agg<64, true, true><<<n / 8, B, 0, stream>>>(
        g, offs, cnt, esrc, dinv, b1, h16, nullptr, n);

    // ---- layer 2: h16 @ W2 -> g ; agg -> h16 ----
    k_gemm_mfma<64, 64, __half><<<(n + 63) / 64, B, 0, stream>>>(h16, wt2, dinv, g, n);
    k_agg<64, true, true><<<n / 8, B, 0, stream>>>(
        g, offs, cnt, esrc, dinv, b2, h16, nullptr, n);

    // ---- layer 3: h16 @ W3 -> g (F=32) ; agg -> out (fp32) ----
    k_gemm_mfma<64, 32, __half><<<(n + 63) / 64, B, 0, stream>>>(h16, wt3, dinv, g, n);
    k_agg<32, false, false><<<n / 16, B, 0, stream>>>(
        g, offs, cnt, esrc, dinv, b3, nullptr, out, n);
}

// Round 13
// 160.710 us; speedup vs baseline: 1.3261x; 1.1273x over previous
//
#include <hip/hip_runtime.h>
#include <hip/hip_fp16.h>

// GCN encoder, 3 layers. g = (X W) * dinv[row] stored FP16.
// out[d] = dinv[d]*(sum_{s->d} g[s] + g[d]) + b, accumulate fp32.
// GEMMs via v_mfma_f32_16x16x16_f16; W pre-transposed fp16 image.
// Aggregate: reduction-free, lane owns 8 features (uint4 = 16B/lane);
// 8 rows in flight per lane = 8KB/wave outstanding (4x R12). Edge lists
// padded to multiples of 8 with dummy idx n pointing at a zeroed row ->
// no tails, int4-aligned index loads. CSR build: fixed-capacity buckets.

#define BSH 7                    // 128 nodes per bucket
#define BNODES (1 << BSH)
#define NBUCKET_MAX 1024
#define CAPSH 12                 // 4096 edge slots per bucket
#define BIN_T 1024
#define BIN_E 4                  // edges per thread in k_bin

typedef __attribute__((ext_vector_type(4))) _Float16 half4v;
typedef __attribute__((ext_vector_type(4))) float float4v;

__global__ void k_binit0(int* __restrict__ bcur, int nb) {
    int b = blockIdx.x * blockDim.x + threadIdx.x;
    if (b < nb) bcur[b] = b << CAPSH;
}

// bin edges into buckets of 128 dst nodes; packed word = (src<<7)|(dst&127).
__global__ __launch_bounds__(BIN_T) void k_bin(
    const int* __restrict__ src, const int* __restrict__ dst,
    int* __restrict__ bcur, unsigned* __restrict__ ebin, int e, int nb) {
    __shared__ int hist[NBUCKET_MAX];
    const int tid = threadIdx.x;
    for (int b = tid; b < nb; b += BIN_T) hist[b] = 0;
    __syncthreads();

    const int base = blockIdx.x * (BIN_T * BIN_E);
    int      bk[BIN_E];
    unsigned pk[BIN_E];
#pragma unroll
    for (int j = 0; j < BIN_E; ++j) {
        int idx = base + j * BIN_T + tid;
        bk[j] = -1;
        if (idx < e) {
            int d = dst[idx], s = src[idx];
            bk[j] = d >> BSH;
            pk[j] = ((unsigned)s << BSH) | (unsigned)(d & (BNODES - 1));
            atomicAdd(&hist[bk[j]], 1);
        }
    }
    __syncthreads();
    for (int b = tid; b < nb; b += BIN_T) {
        int c = hist[b];
        hist[b] = c ? atomicAdd(&bcur[b], c) : 0;   // hist now = running cursor
    }
    __syncthreads();
#pragma unroll
    for (int j = 0; j < BIN_E; ++j) {
        if (bk[j] >= 0) {
            int pos = atomicAdd(&hist[bk[j]], 1);
            ebin[pos] = pk[j];
        }
    }
}

// per bucket: LDS node-histogram + 128-scan (8-padded) -> per-node
// cnt(padded)/offs/dinv; fill slice with dummy idx n; scatter real srcs.
__global__ __launch_bounds__(256) void k_place2(
    const unsigned* __restrict__ ebin, const int* __restrict__ bcur,
    int* __restrict__ esrc, int* __restrict__ cnt, int* __restrict__ offs,
    float* __restrict__ dinv, int n) {
    __shared__ int hist[BNODES];
    __shared__ int loff[BNODES];
    __shared__ int cur[BNODES];
    const int b = blockIdx.x, tid = threadIdx.x;
    const int node0 = b << BSH;
    const int start = b << CAPSH;
    const int end   = bcur[b];
    if (tid < BNODES) hist[tid] = 0;
    __syncthreads();
    for (int j = start + tid; j < end; j += 256)
        atomicAdd(&hist[ebin[j] & (BNODES - 1)], 1);
    __syncthreads();
    int v  = (tid < BNODES) ? hist[tid] : 0;
    int vp = (v + 7) & ~7;              // pad each node's list to 8
    if (tid < BNODES) loff[tid] = vp;
    __syncthreads();
    for (int off = 1; off < BNODES; off <<= 1) {
        int add = (tid < BNODES && tid >= off) ? loff[tid - off] : 0;
        __syncthreads();
        if (tid < BNODES) loff[tid] += add;
        __syncthreads();
    }
    if (tid < BNODES) {
        int o = start + loff[tid] - vp;  // exclusive, bucket-strided, 8-aligned
        cur[tid] = o;
        int node = node0 + tid;
        if (node < n) {
            cnt[node]  = vp;             // padded count = agg loop bound
            offs[node] = o;
            dinv[node] = rsqrtf((float)(v + 1));  // real degree + self-loop
        }
    }
    __syncthreads();
    const int total = loff[BNODES - 1];
    for (int i = start + tid; i < start + total; i += 256)
        esrc[i] = n;                     // dummy -> zeroed row
    __syncthreads();
    for (int j = start + tid; j < end; j += 256) {
        unsigned p = ebin[j];
        int pos = atomicAdd(&cur[p & (BNODES - 1)], 1);
        esrc[pos] = (int)(p >> BSH);
    }
}

// prep: W[k][f] (fp32) -> wt_img[f][k] (fp16, row stride K+8, LDS-ready);
// also zero the dummy rows g[n] (64 halves) and g3[n] (32 halves).
__global__ __launch_bounds__(256) void k_wprep(
    const float* __restrict__ W1, const float* __restrict__ W2,
    const float* __restrict__ W3, __half* __restrict__ wt1,
    __half* __restrict__ wt2, __half* __restrict__ wt3,
    __half* __restrict__ g, __half* __restrict__ g3, int n) {
    int gid = blockIdx.x * 256 + threadIdx.x;
    if (gid < 8192) {                       // W1: 128x64, KP=136
        int k = gid >> 6, f = gid & 63;
        wt1[f * 136 + k] = __float2half(W1[gid]);
    } else if (gid < 12288) {               // W2: 64x64, KP=72
        int i = gid - 8192;
        int k = i >> 6, f = i & 63;
        wt2[f * 72 + k] = __float2half(W2[i]);
    } else if (gid < 14336) {               // W3: 64x32, KP=72
        int i = gid - 12288;
        int k = i >> 5, f = i & 31;
        wt3[f * 72 + k] = __float2half(W3[i]);
    } else if (gid < 14400) {               // dummy row of g (F=64)
        g[(size_t)n * 64 + (gid - 14336)] = __float2half(0.f);
    } else if (gid < 14432) {               // dummy row of g3 (F=32)
        g3[(size_t)n * 32 + (gid - 14400)] = __float2half(0.f);
    }
}

// MFMA GEMM: g[node][f] = fp16( dinv[node] * sum_k in[node][k] * W[k][f] )
// 64-node tile per block, 4 waves x 16 rows; v_mfma_f32_16x16x16_f16.
// W comes pre-transposed/padded (wt_img, stride KP) -> flat uint4 copy.
template <int K, int F, typename InT>
__global__ __launch_bounds__(256) void k_gemm_mfma(
    const InT* __restrict__ in, const __half* __restrict__ wt_img,
    const float* __restrict__ dinv, __half* __restrict__ g, int n) {
    constexpr int KP = K + 8;         // padded halves per row
    constexpr int FP = F + 8;
    constexpr int NT = 64;            // nodes per block
    constexpr int CT = F / 16;        // col tiles per wave
    __shared__ __align__(16) __half xs[NT][KP];
    __shared__ __align__(16) __half wt[F][KP];   // wt[f][k] = W[k][f]
    const int tid = threadIdx.x;
    const int node0 = blockIdx.x * NT;

    // stage x tile -> fp16
    if constexpr (sizeof(InT) == 4) {
        constexpr int KW = K / 4;     // float4 per row
        const float4* in4 = reinterpret_cast<const float4*>(in);
        for (int i = tid; i < NT * KW; i += 256) {
            int r = i / KW, c = (i % KW) * 4;
            if (node0 + r < n) {
                float4 v = in4[(size_t)(node0 + r) * KW + (i % KW)];
                union { __half2 h2[2]; uint2 u; } pk;
                pk.h2[0] = __floats2half2_rn(v.x, v.y);
                pk.h2[1] = __floats2half2_rn(v.z, v.w);
                *reinterpret_cast<uint2*>(&xs[r][c]) = pk.u;
            }
        }
    } else {
        constexpr int KW = K / 8;     // uint4 per row
        const uint4* in4 = reinterpret_cast<const uint4*>(in);
        for (int i = tid; i < NT * KW; i += 256) {
            int r = i / KW, c = (i % KW) * 8;
            if (node0 + r < n)
                *reinterpret_cast<uint4*>(&xs[r][c]) =
                    in4[(size_t)(node0 + r) * KW + (i % KW)];
        }
    }
    // stage W image (already transposed fp16, stride KP): flat copy
    {
        const uint4* wim = reinterpret_cast<const uint4*>(wt_img);
        uint4* wt4 = reinterpret_cast<uint4*>(&wt[0][0]);
        for (int i = tid; i < F * KP / 8; i += 256) wt4[i] = wim[i];
    }
    __syncthreads();

    const int wid = tid >> 6, lane = tid & 63;
    const int rl = lane & 15;         // row within row-tile / col within col-tile
    const int kb = (lane >> 4) * 4;   // k base for this lane
    const int arow = wid * 16 + rl;

    float4v acc[CT];
#pragma unroll
    for (int c = 0; c < CT; ++c) acc[c] = (float4v)(0.f);

#pragma unroll
    for (int kk = 0; kk < K / 16; ++kk) {
        union { uint2 u; half4v h; } a;
        a.u = *reinterpret_cast<const uint2*>(&xs[arow][kk * 16 + kb]);
#pragma unroll
        for (int c = 0; c < CT; ++c) {
            union { uint2 u; half4v h; } b;
            b.u = *reinterpret_cast<const uint2*>(&wt[c * 16 + rl][kk * 16 + kb]);
            acc[c] = __builtin_amdgcn_mfma_f32_16x16x16f16(a.h, b.h, acc[c], 0, 0, 0);
        }
    }
    __syncthreads();   // xs dead; reuse as hs

    __half (*hs)[FP] = reinterpret_cast<__half (*)[FP]>(&xs[0][0]);
    float dv[4];
#pragma unroll
    for (int i = 0; i < 4; ++i) {
        int r = wid * 16 + (lane >> 4) * 4 + i;
        dv[i] = (node0 + r < n) ? dinv[node0 + r] : 0.f;
    }
#pragma unroll
    for (int c = 0; c < CT; ++c)
#pragma unroll
        for (int i = 0; i < 4; ++i) {
            int r = wid * 16 + (lane >> 4) * 4 + i;
            hs[r][c * 16 + rl] = __float2half(acc[c][i] * dv[i]);
        }
    __syncthreads();
    // coalesced writeout: uint4 = 8 halves
    constexpr int FW = F / 8;
    for (int i = tid; i < NT * FW; i += 256) {
        int r = i / FW, c = (i % FW) * 8;
        if (node0 + r < n)
            *reinterpret_cast<uint4*>(&g[(size_t)(node0 + r) * F + c]) =
                *reinterpret_cast<const uint4*>(&hs[r][c]);
    }
}

__device__ inline void h8_acc(uint4 u, float* a) {
    const __half2* h = reinterpret_cast<const __half2*>(&u);
#pragma unroll
    for (int i = 0; i < 4; ++i) {
        float2 f = __half22float2(h[i]);
        a[2 * i]     += f.x;
        a[2 * i + 1] += f.y;
    }
}

// pairwise fp16 pre-sum of two rows, then fp32 accumulate (R9-proven)
__device__ inline void h8_acc2(uint4 ua, uint4 ub, float* a) {
    const __half2* ha = reinterpret_cast<const __half2*>(&ua);
    const __half2* hb = reinterpret_cast<const __half2*>(&ub);
#pragma unroll
    for (int i = 0; i < 4; ++i) {
        __half2 s = __hadd2(ha[i], hb[i]);
        float2 f = __half22float2(s);
        a[2 * i]     += f.x;
        a[2 * i + 1] += f.y;
    }
}

// Aggregate + finalize, reduction-free. Lane owns 8 features (uint4) of its
// node; F/8 lanes per node, 64/(F/8) nodes per wave. Edge lists are 8-padded
// (dummy idx n -> zero row): no tails. 8 rows (8KB/wave) + 2 int4 idx loads
// in flight. HOUT: write fp16 h row; else fp32 to fout.
template <int F, bool RELU, bool HOUT>
__global__ __launch_bounds__(256, 6) void k_agg(
    const __half* __restrict__ gin, const int* __restrict__ offs,
    const int* __restrict__ cnt, const int* __restrict__ esrc,
    const float* __restrict__ dinv, const float* __restrict__ bias,
    __half* __restrict__ hout, float* __restrict__ fout, int n) {
    constexpr int LPN = F / 8;          // lanes per node (uint4 each)
    constexpr int NPW = 64 / LPN;       // nodes per wave
    constexpr int RS  = F / 8;          // row stride in uint4
    const int wid  = threadIdx.x >> 6;
    const int lane = threadIdx.x & 63;
    const int sub  = lane / LPN;
    const int fl   = lane % LPN;
    const int node = (blockIdx.x * 4 + wid) * NPW + sub;
    if (node >= n) return;
    const int start = offs[node];       // multiple of 8
    const int m     = cnt[node];        // padded to multiple of 8
    const uint4* gp = reinterpret_cast<const uint4*>(gin) + fl;

    float acc[8];
#pragma unroll
    for (int i = 0; i < 8; ++i) acc[i] = 0.f;

    for (int j = 0; j < m; j += 8) {    // 2 idx + 8 row loads in flight
        int4 ia = *reinterpret_cast<const int4*>(esrc + start + j);
        int4 ib = *reinterpret_cast<const int4*>(esrc + start + j + 4);
        uint4 r0 = gp[(size_t)ia.x * RS];
        uint4 r1 = gp[(size_t)ia.y * RS];
        uint4 r2 = gp[(size_t)ia.z * RS];
        uint4 r3 = gp[(size_t)ia.w * RS];
        uint4 r4 = gp[(size_t)ib.x * RS];
        uint4 r5 = gp[(size_t)ib.y * RS];
        uint4 r6 = gp[(size_t)ib.z * RS];
        uint4 r7 = gp[(size_t)ib.w * RS];
        h8_acc2(r0, r1, acc);
        h8_acc2(r2, r3, acc);
        h8_acc2(r4, r5, acc);
        h8_acc2(r6, r7, acc);
    }

    float sv[8];
#pragma unroll
    for (int i = 0; i < 8; ++i) sv[i] = 0.f;
    h8_acc(gp[(size_t)node * RS], sv);   // self-loop
    const float dv = dinv[node];
    float4 b0 = *reinterpret_cast<const float4*>(bias + fl * 8);
    float4 b1 = *reinterpret_cast<const float4*>(bias + fl * 8 + 4);
    float bb[8] = {b0.x, b0.y, b0.z, b0.w, b1.x, b1.y, b1.z, b1.w};
    float rr[8];
#pragma unroll
    for (int i = 0; i < 8; ++i) {
        rr[i] = dv * (acc[i] + sv[i]) + bb[i];
        if (RELU) rr[i] = fmaxf(rr[i], 0.f);
    }
    if (HOUT) {
        union { __half2 h2[4]; uint4 u; } pk;
#pragma unroll
        for (int i = 0; i < 4; ++i)
            pk.h2[i] = __floats2half2_rn(rr[2 * i], rr[2 * i + 1]);
        reinterpret_cast<uint4*>(hout)[(size_t)node * RS + fl] = pk.u;
    } else {
        float4 o0 = {rr[0], rr[1], rr[2], rr[3]};
        float4 o1 = {rr[4], rr[5], rr[6], rr[7]};
        float4* fo = reinterpret_cast<float4*>(fout) + (size_t)node * (F / 4) + fl * 2;
        fo[0] = o0;
        fo[1] = o1;
    }
}

extern "C" void kernel_launch(void* const* d_in, const int* in_sizes, int n_in,
                              void* d_out, int out_size, void* d_ws, size_t ws_size,
                              hipStream_t stream) {
    const float* x  = (const float*)d_in[0];
    const int*   ei = (const int*)d_in[1];
    const float* W1 = (const float*)d_in[2];
    const float* b1 = (const float*)d_in[3];
    const float* W2 = (const float*)d_in[4];
    const float* b2 = (const float*)d_in[5];
    const float* W3 = (const float*)d_in[6];
    const float* b3 = (const float*)d_in[7];
    float* out = (float*)d_out;

    const int n = in_sizes[0] / 128;   // 100000
    const int e = in_sizes[1] / 2;     // 1600000
    const int* src = ei;
    const int* dst = ei + e;

    const int nb = (n + BNODES - 1) >> BSH;  // 782

    // workspace layout (4-byte units)
    float*    dinv = (float*)d_ws;                       // n
    __half*   g    = (__half*)(dinv + n);                // (n+1)*64 halves
    __half*   h16  = (__half*)((int*)d_ws + n + (size_t)n * 32 + 32);  // n*64 halves
    __half*   g3   = h16 + (size_t)n * 64;               // (n+1)*32 halves
    int*      cnt  = (int*)(g3 + (size_t)n * 32 + 32);   // n
    int*      offs = cnt + n;                            // n
    int*      bcur = offs + n;                           // NBUCKET_MAX
    __half*   wt1  = (__half*)(bcur + NBUCKET_MAX);      // 64*136 halves
    __half*   wt2  = wt1 + 64 * 136;                     // 64*72
    __half*   wt3  = wt2 + 64 * 72;                      // 32*72
    unsigned* ebin = (unsigned*)(wt3 + 32 * 72 + 32);    // nb<<CAPSH
    int*      esrc = (int*)(ebin + ((size_t)nb << CAPSH));  // nb<<CAPSH

    const int B = 256;
    const int binGrid = (e + BIN_T * BIN_E - 1) / (BIN_T * BIN_E);

    // ---- CSR build (fixed-capacity buckets; emits cnt/offs/dinv) + W prep ----
    k_binit0<<<(nb + B - 1) / B, B, 0, stream>>>(bcur, nb);
    k_wprep<<<57, B, 0, stream>>>(W1, W2, W3, wt1, wt2, wt3, g, g3, n);
    k_bin<<<binGrid, BIN_T, 0, stream>>>(src, dst, bcur, ebin, e, nb);
    k_place2<<<nb, B, 0, stream>>>(ebin, bcur, esrc, cnt, offs, dinv, n);

    // ---- layer 1: x[n x 128] @ W1 -> g (fp16) ; agg -> h16 (fp16) ----
    k_gemm_mfma<128, 64, float><<<(n + 63) / 64, B, 0, stream>>>(x, wt1, dinv, g, n);
    k_agg<64, true, true><<<n / 32, B, 0, stream>>>(
        g, offs, cnt, esrc, dinv, b1, h16, nullptr, n);

    // ---- layer 2: h16 @ W2 -> g ; agg -> h16 ----
    k_gemm_mfma<64, 64, __half><<<(n + 63) / 64, B, 0, stream>>>(h16, wt2, dinv, g, n);
    k_agg<64, true, true><<<n / 32, B, 0, stream>>>(
        g, offs, cnt, esrc, dinv, b2, h16, nullptr, n);

    // ---- layer 3: h16 @ W3 -> g3 (F=32) ; agg -> out (fp32) ----
    k_gemm_mfma<64, 32, __half><<<(n + 63) / 64, B, 0, stream>>>(h16, wt3, dinv, g3, n);
    k_agg<32, false, false><<<(n + 63) / 64, B, 0, stream>>>(
        g3, offs, cnt, esrc, dinv, b3, nullptr, out, n);
}

// Round 14
// 154.575 us; speedup vs baseline: 1.3787x; 1.0397x over previous
//
#include <hip/hip_runtime.h>
#include <hip/hip_fp16.h>

// GCN encoder, 3 layers. g = (X W) * dinv[row] stored FP16.
// out[d] = dinv[d]*(sum_{s->d} g[s] + g[d]) + b, accumulate fp32.
// GEMMs via v_mfma_f32_16x16x16_f16; W pre-transposed fp16 image.
// Aggregate: reduction-free, lane owns 8 features (uint4), 8 rows +
// prefetched next-iteration indices in flight; 8-padded edge lists.
// CSR build: fixed-capacity buckets; BIN_E=13 for write-combining.

#define BSH 7                    // 128 nodes per bucket
#define BNODES (1 << BSH)
#define NBUCKET_MAX 1024
#define CAPSH 12                 // 4096 edge slots per bucket
#define BIN_T 1024
#define BIN_E 13                 // edges per thread in k_bin

typedef __attribute__((ext_vector_type(4))) _Float16 half4v;
typedef __attribute__((ext_vector_type(4))) float float4v;

// bin edges into buckets of 128 dst nodes; packed word = (src<<7)|(dst&127).
__global__ __launch_bounds__(BIN_T) void k_bin(
    const int* __restrict__ src, const int* __restrict__ dst,
    int* __restrict__ bcur, unsigned* __restrict__ ebin, int e, int nb) {
    __shared__ int hist[NBUCKET_MAX];
    const int tid = threadIdx.x;
    for (int b = tid; b < nb; b += BIN_T) hist[b] = 0;
    __syncthreads();

    const int base = blockIdx.x * (BIN_T * BIN_E);
    int      bk[BIN_E];
    unsigned pk[BIN_E];
#pragma unroll
    for (int j = 0; j < BIN_E; ++j) {
        int idx = base + j * BIN_T + tid;
        bk[j] = -1;
        if (idx < e) {
            int d = dst[idx], s = src[idx];
            bk[j] = d >> BSH;
            pk[j] = ((unsigned)s << BSH) | (unsigned)(d & (BNODES - 1));
            atomicAdd(&hist[bk[j]], 1);
        }
    }
    __syncthreads();
    for (int b = tid; b < nb; b += BIN_T) {
        int c = hist[b];
        hist[b] = c ? atomicAdd(&bcur[b], c) : 0;   // hist now = running cursor
    }
    __syncthreads();
#pragma unroll
    for (int j = 0; j < BIN_E; ++j) {
        if (bk[j] >= 0) {
            int pos = atomicAdd(&hist[bk[j]], 1);
            ebin[pos] = pk[j];
        }
    }
}

// per bucket: LDS node-histogram + 128-scan (8-padded) -> per-node
// cnt(padded)/offs/dinv; fill slice with dummy idx n; scatter real srcs.
__global__ __launch_bounds__(512) void k_place2(
    const unsigned* __restrict__ ebin, const int* __restrict__ bcur,
    int* __restrict__ esrc, int* __restrict__ cnt, int* __restrict__ offs,
    float* __restrict__ dinv, int n) {
    __shared__ int hist[BNODES];
    __shared__ int loff[BNODES];
    __shared__ int cur[BNODES];
    const int b = blockIdx.x, tid = threadIdx.x;
    const int node0 = b << BSH;
    const int start = b << CAPSH;
    const int end   = bcur[b];
    if (tid < BNODES) hist[tid] = 0;
    __syncthreads();
    for (int j = start + tid; j < end; j += 512)
        atomicAdd(&hist[ebin[j] & (BNODES - 1)], 1);
    __syncthreads();
    int v  = (tid < BNODES) ? hist[tid] : 0;
    int vp = (v + 7) & ~7;              // pad each node's list to 8
    if (tid < BNODES) loff[tid] = vp;
    __syncthreads();
    for (int off = 1; off < BNODES; off <<= 1) {
        int add = (tid < BNODES && tid >= off) ? loff[tid - off] : 0;
        __syncthreads();
        if (tid < BNODES) loff[tid] += add;
        __syncthreads();
    }
    if (tid < BNODES) {
        int o = start + loff[tid] - vp;  // exclusive, bucket-strided, 8-aligned
        cur[tid] = o;
        int node = node0 + tid;
        if (node < n) {
            cnt[node]  = vp;             // padded count = agg loop bound
            offs[node] = o;
            dinv[node] = rsqrtf((float)(v + 1));  // real degree + self-loop
        }
    }
    __syncthreads();
    const int total = loff[BNODES - 1];
    for (int i = start + tid; i < start + total; i += 512)
        esrc[i] = n;                     // dummy -> zeroed row
    __syncthreads();
    for (int j = start + tid; j < end; j += 512) {
        unsigned p = ebin[j];
        int pos = atomicAdd(&cur[p & (BNODES - 1)], 1);
        esrc[pos] = (int)(p >> BSH);
    }
}

// prep: W images (fp16, transposed, stride K+8) + dummy zero rows + bcur init
__global__ __launch_bounds__(256) void k_wprep(
    const float* __restrict__ W1, const float* __restrict__ W2,
    const float* __restrict__ W3, __half* __restrict__ wt1,
    __half* __restrict__ wt2, __half* __restrict__ wt3,
    __half* __restrict__ g, __half* __restrict__ g3,
    int* __restrict__ bcur, int n, int nb) {
    int gid = blockIdx.x * 256 + threadIdx.x;
    if (gid < 8192) {                       // W1: 128x64, KP=136
        int k = gid >> 6, f = gid & 63;
        wt1[f * 136 + k] = __float2half(W1[gid]);
    } else if (gid < 12288) {               // W2: 64x64, KP=72
        int i = gid - 8192;
        int k = i >> 6, f = i & 63;
        wt2[f * 72 + k] = __float2half(W2[i]);
    } else if (gid < 14336) {               // W3: 64x32, KP=72
        int i = gid - 12288;
        int k = i >> 5, f = i & 31;
        wt3[f * 72 + k] = __float2half(W3[i]);
    } else if (gid < 14400) {               // dummy row of g (F=64)
        g[(size_t)n * 64 + (gid - 14336)] = __float2half(0.f);
    } else if (gid < 14432) {               // dummy row of g3 (F=32)
        g3[(size_t)n * 32 + (gid - 14400)] = __float2half(0.f);
    } else if (gid < 14432 + nb) {          // bucket cursors
        int b = gid - 14432;
        bcur[b] = b << CAPSH;
    }
}

// MFMA GEMM: g[node][f] = fp16( dinv[node] * sum_k in[node][k] * W[k][f] )
// 64-node tile per block, 4 waves x 16 rows; v_mfma_f32_16x16x16_f16.
template <int K, int F, typename InT>
__global__ __launch_bounds__(256) void k_gemm_mfma(
    const InT* __restrict__ in, const __half* __restrict__ wt_img,
    const float* __restrict__ dinv, __half* __restrict__ g, int n) {
    constexpr int KP = K + 8;         // padded halves per row
    constexpr int FP = F + 8;
    constexpr int NT = 64;            // nodes per block
    constexpr int CT = F / 16;        // col tiles per wave
    __shared__ __align__(16) __half xs[NT][KP];
    __shared__ __align__(16) __half wt[F][KP];   // wt[f][k] = W[k][f]
    const int tid = threadIdx.x;
    const int node0 = blockIdx.x * NT;

    // stage x tile -> fp16
    if constexpr (sizeof(InT) == 4) {
        constexpr int KW = K / 4;     // float4 per row
        const float4* in4 = reinterpret_cast<const float4*>(in);
        for (int i = tid; i < NT * KW; i += 256) {
            int r = i / KW, c = (i % KW) * 4;
            if (node0 + r < n) {
                float4 v = in4[(size_t)(node0 + r) * KW + (i % KW)];
                union { __half2 h2[2]; uint2 u; } pk;
                pk.h2[0] = __floats2half2_rn(v.x, v.y);
                pk.h2[1] = __floats2half2_rn(v.z, v.w);
                *reinterpret_cast<uint2*>(&xs[r][c]) = pk.u;
            }
        }
    } else {
        constexpr int KW = K / 8;     // uint4 per row
        const uint4* in4 = reinterpret_cast<const uint4*>(in);
        for (int i = tid; i < NT * KW; i += 256) {
            int r = i / KW, c = (i % KW) * 8;
            if (node0 + r < n)
                *reinterpret_cast<uint4*>(&xs[r][c]) =
                    in4[(size_t)(node0 + r) * KW + (i % KW)];
        }
    }
    // stage W image (already transposed fp16, stride KP): flat copy
    {
        const uint4* wim = reinterpret_cast<const uint4*>(wt_img);
        uint4* wt4 = reinterpret_cast<uint4*>(&wt[0][0]);
        for (int i = tid; i < F * KP / 8; i += 256) wt4[i] = wim[i];
    }
    __syncthreads();

    const int wid = tid >> 6, lane = tid & 63;
    const int rl = lane & 15;         // row within row-tile / col within col-tile
    const int kb = (lane >> 4) * 4;   // k base for this lane
    const int arow = wid * 16 + rl;

    float4v acc[CT];
#pragma unroll
    for (int c = 0; c < CT; ++c) acc[c] = (float4v)(0.f);

#pragma unroll
    for (int kk = 0; kk < K / 16; ++kk) {
        union { uint2 u; half4v h; } a;
        a.u = *reinterpret_cast<const uint2*>(&xs[arow][kk * 16 + kb]);
#pragma unroll
        for (int c = 0; c < CT; ++c) {
            union { uint2 u; half4v h; } b;
            b.u = *reinterpret_cast<const uint2*>(&wt[c * 16 + rl][kk * 16 + kb]);
            acc[c] = __builtin_amdgcn_mfma_f32_16x16x16f16(a.h, b.h, acc[c], 0, 0, 0);
        }
    }
    __syncthreads();   // xs dead; reuse as hs

    __half (*hs)[FP] = reinterpret_cast<__half (*)[FP]>(&xs[0][0]);
    float dv[4];
#pragma unroll
    for (int i = 0; i < 4; ++i) {
        int r = wid * 16 + (lane >> 4) * 4 + i;
        dv[i] = (node0 + r < n) ? dinv[node0 + r] : 0.f;
    }
#pragma unroll
    for (int c = 0; c < CT; ++c)
#pragma unroll
        for (int i = 0; i < 4; ++i) {
            int r = wid * 16 + (lane >> 4) * 4 + i;
            hs[r][c * 16 + rl] = __float2half(acc[c][i] * dv[i]);
        }
    __syncthreads();
    // coalesced writeout: uint4 = 8 halves
    constexpr int FW = F / 8;
    for (int i = tid; i < NT * FW; i += 256) {
        int r = i / FW, c = (i % FW) * 8;
        if (node0 + r < n)
            *reinterpret_cast<uint4*>(&g[(size_t)(node0 + r) * F + c]) =
                *reinterpret_cast<const uint4*>(&hs[r][c]);
    }
}

__device__ inline void h8_acc(uint4 u, float* a) {
    const __half2* h = reinterpret_cast<const __half2*>(&u);
#pragma unroll
    for (int i = 0; i < 4; ++i) {
        float2 f = __half22float2(h[i]);
        a[2 * i]     += f.x;
        a[2 * i + 1] += f.y;
    }
}

// pairwise fp16 pre-sum of two rows, then fp32 accumulate (R9-proven)
__device__ inline void h8_acc2(uint4 ua, uint4 ub, float* a) {
    const __half2* ha = reinterpret_cast<const __half2*>(&ua);
    const __half2* hb = reinterpret_cast<const __half2*>(&ub);
#pragma unroll
    for (int i = 0; i < 4; ++i) {
        __half2 s = __hadd2(ha[i], hb[i]);
        float2 f = __half22float2(s);
        a[2 * i]     += f.x;
        a[2 * i + 1] += f.y;
    }
}

// Aggregate + finalize, reduction-free. Lane owns 8 features (uint4) of its
// node; 8-padded edge lists (dummy idx n -> zero row). Next iteration's
// index words are prefetched while current rows are summed.
template <int F, bool RELU, bool HOUT>
__global__ __launch_bounds__(256, 6) void k_agg(
    const __half* __restrict__ gin, const int* __restrict__ offs,
    const int* __restrict__ cnt, const int* __restrict__ esrc,
    const float* __restrict__ dinv, const float* __restrict__ bias,
    __half* __restrict__ hout, float* __restrict__ fout, int n) {
    constexpr int LPN = F / 8;          // lanes per node (uint4 each)
    constexpr int NPW = 64 / LPN;       // nodes per wave
    constexpr int RS  = F / 8;          // row stride in uint4
    const int wid  = threadIdx.x >> 6;
    const int lane = threadIdx.x & 63;
    const int sub  = lane / LPN;
    const int fl   = lane % LPN;
    const int node = (blockIdx.x * 4 + wid) * NPW + sub;
    if (node >= n) return;
    const int start = offs[node];       // multiple of 8
    const int m     = cnt[node];        // padded to multiple of 8
    const uint4* gp = reinterpret_cast<const uint4*>(gin) + fl;

    float acc[8];
#pragma unroll
    for (int i = 0; i < 8; ++i) acc[i] = 0.f;

    int4 ia = {0, 0, 0, 0}, ib = {0, 0, 0, 0};
    if (m > 0) {
        ia = *reinterpret_cast<const int4*>(esrc + start);
        ib = *reinterpret_cast<const int4*>(esrc + start + 4);
    }
    for (int j = 0; j < m; j += 8) {
        uint4 r0 = gp[(size_t)ia.x * RS];
        uint4 r1 = gp[(size_t)ia.y * RS];
        uint4 r2 = gp[(size_t)ia.z * RS];
        uint4 r3 = gp[(size_t)ia.w * RS];
        uint4 r4 = gp[(size_t)ib.x * RS];
        uint4 r5 = gp[(size_t)ib.y * RS];
        uint4 r6 = gp[(size_t)ib.z * RS];
        uint4 r7 = gp[(size_t)ib.w * RS];
        if (j + 8 < m) {                 // prefetch next indices under row loads
            ia = *reinterpret_cast<const int4*>(esrc + start + j + 8);
            ib = *reinterpret_cast<const int4*>(esrc + start + j + 12);
        }
        h8_acc2(r0, r1, acc);
        h8_acc2(r2, r3, acc);
        h8_acc2(r4, r5, acc);
        h8_acc2(r6, r7, acc);
    }

    float sv[8];
#pragma unroll
    for (int i = 0; i < 8; ++i) sv[i] = 0.f;
    h8_acc(gp[(size_t)node * RS], sv);   // self-loop
    const float dv = dinv[node];
    float4 b0 = *reinterpret_cast<const float4*>(bias + fl * 8);
    float4 b1 = *reinterpret_cast<const float4*>(bias + fl * 8 + 4);
    float bb[8] = {b0.x, b0.y, b0.z, b0.w, b1.x, b1.y, b1.z, b1.w};
    float rr[8];
#pragma unroll
    for (int i = 0; i < 8; ++i) {
        rr[i] = dv * (acc[i] + sv[i]) + bb[i];
        if (RELU) rr[i] = fmaxf(rr[i], 0.f);
    }
    if (HOUT) {
        union { __half2 h2[4]; uint4 u; } pk;
#pragma unroll
        for (int i = 0; i < 4; ++i)
            pk.h2[i] = __floats2half2_rn(rr[2 * i], rr[2 * i + 1]);
        reinterpret_cast<uint4*>(hout)[(size_t)node * RS + fl] = pk.u;
    } else {
        float4 o0 = {rr[0], rr[1], rr[2], rr[3]};
        float4 o1 = {rr[4], rr[5], rr[6], rr[7]};
        float4* fo = reinterpret_cast<float4*>(fout) + (size_t)node * (F / 4) + fl * 2;
        fo[0] = o0;
        fo[1] = o1;
    }
}

extern "C" void kernel_launch(void* const* d_in, const int* in_sizes, int n_in,
                              void* d_out, int out_size, void* d_ws, size_t ws_size,
                              hipStream_t stream) {
    const float* x  = (const float*)d_in[0];
    const int*   ei = (const int*)d_in[1];
    const float* W1 = (const float*)d_in[2];
    const float* b1 = (const float*)d_in[3];
    const float* W2 = (const float*)d_in[4];
    const float* b2 = (const float*)d_in[5];
    const float* W3 = (const float*)d_in[6];
    const float* b3 = (const float*)d_in[7];
    float* out = (float*)d_out;

    const int n = in_sizes[0] / 128;   // 100000
    const int e = in_sizes[1] / 2;     // 1600000
    const int* src = ei;
    const int* dst = ei + e;

    const int nb = (n + BNODES - 1) >> BSH;  // 782

    // workspace layout (4-byte units)
    float*    dinv = (float*)d_ws;                       // n
    __half*   g    = (__half*)(dinv + n);                // (n+1)*64 halves
    __half*   h16  = (__half*)((int*)d_ws + n + (size_t)n * 32 + 32);  // n*64 halves
    __half*   g3   = h16 + (size_t)n * 64;               // (n+1)*32 halves
    int*      cnt  = (int*)(g3 + (size_t)n * 32 + 32);   // n
    int*      offs = cnt + n;                            // n
    int*      bcur = offs + n;                           // NBUCKET_MAX
    __half*   wt1  = (__half*)(bcur + NBUCKET_MAX);      // 64*136 halves
    __half*   wt2  = wt1 + 64 * 136;                     // 64*72
    __half*   wt3  = wt2 + 64 * 72;                      // 32*72
    unsigned* ebin = (unsigned*)(wt3 + 32 * 72 + 32);    // nb<<CAPSH
    int*      esrc = (int*)(ebin + ((size_t)nb << CAPSH));  // nb<<CAPSH

    const int B = 256;
    const int binGrid = (e + BIN_T * BIN_E - 1) / (BIN_T * BIN_E);

    // ---- W prep + bucket cursors, then CSR build ----
    k_wprep<<<60, B, 0, stream>>>(W1, W2, W3, wt1, wt2, wt3, g, g3, bcur, n, nb);
    k_bin<<<binGrid, BIN_T, 0, stream>>>(src, dst, bcur, ebin, e, nb);
    k_place2<<<nb, 512, 0, stream>>>(ebin, bcur, esrc, cnt, offs, dinv, n);

    // ---- layer 1: x[n x 128] @ W1 -> g (fp16) ; agg -> h16 (fp16) ----
    k_gemm_mfma<128, 64, float><<<(n + 63) / 64, B, 0, stream>>>(x, wt1, dinv, g, n);
    k_agg<64, true, true><<<n / 32, B, 0, stream>>>(
        g, offs, cnt, esrc, dinv, b1, h16, nullptr, n);

    // ---- layer 2: h16 @ W2 -> g ; agg -> h16 ----
    k_gemm_mfma<64, 64, __half><<<(n + 63) / 64, B, 0, stream>>>(h16, wt2, dinv, g, n);
    k_agg<64, true, true><<<n / 32, B, 0, stream>>>(
        g, offs, cnt, esrc, dinv, b2, h16, nullptr, n);

    // ---- layer 3: h16 @ W3 -> g3 (F=32) ; agg -> out (fp32) ----
    k_gemm_mfma<64, 32, __half><<<(n + 63) / 64, B, 0, stream>>>(h16, wt3, dinv, g3, n);
    k_agg<32, false, false><<<(n + 63) / 64, B, 0, stream>>>(
        g3, offs, cnt, esrc, dinv, b3, nullptr, out, n);
}